// Round 11
// baseline (1008.875 us; speedup 1.0000x reference)
//
#include <hip/hip_runtime.h>
#include <hip/hip_fp16.h>

#define N_NODESC 50000
#define N_EDGESC 1600000
#define FEAT 128
#define NREL 8
#define NSEG (N_NODESC * NREL)
#define NGRAPH 64
#define KTOT 1152          // 8*128 agg + 128 root
#define NKC 36             // KTOT/32
#define WPACK_ELEMS (NKC * 4 * 128 * 8)  // 147456
#define NHALF (N_NODESC * FEAT)

typedef float f32x4 __attribute__((ext_vector_type(4)));
typedef _Float16 f16x8 __attribute__((ext_vector_type(8)));

static inline size_t align256(size_t x) { return (x + 255) & ~(size_t)255; }

__device__ __forceinline__ float4 h4tof4(uint2 r) {
  const __half* h = (const __half*)&r;
  return make_float4(__half2float(h[0]), __half2float(h[1]),
                     __half2float(h[2]), __half2float(h[3]));
}

// ---------------- utility: zero ints ----------------
__global__ void k_zero(int* __restrict__ p, int n) {
  int i = blockIdx.x * blockDim.x + threadIdx.x;
  int stride = gridDim.x * blockDim.x;
  for (; i < n; i += stride) p[i] = 0;
}

// ---------------- fp32 -> fp16 plane ----------------
__global__ void k_cvt16(const float* __restrict__ in, __half* __restrict__ o) {
  int i = blockIdx.x * blockDim.x + threadIdx.x;
  if (i * 4 >= NHALF) return;
  float4 v = *(const float4*)&in[i * 4];
  __half h[4] = {__float2half(v.x), __float2half(v.y), __float2half(v.z), __float2half(v.w)};
  *(uint2*)&o[(size_t)i * 4] = *(uint2*)h;
}

// ---------------- edge type + segment + histogram ----------------
__global__ void k_edge_hist(const int* __restrict__ ei, const float* __restrict__ eattr,
                            int* __restrict__ seg, int* __restrict__ cnt) {
  int e = blockIdx.x * blockDim.x + threadIdx.x;
  if (e >= N_EDGESC) return;
  int dst = ei[N_EDGESC + e];
  const float4* ap = (const float4*)(eattr + (size_t)e * 8);
  float4 a0 = ap[0], a1 = ap[1];
  int ty = 0;
  if (a0.y > 0.5f) ty = 1;
  if (a0.z > 0.5f) ty = 2;
  if (a0.w > 0.5f) ty = 3;
  if (a1.x > 0.5f) ty = 4;
  if (a1.y > 0.5f) ty = 5;
  if (a1.z > 0.5f) ty = 6;
  if (a1.w > 0.5f) ty = 7;
  int s = dst * NREL + ty;
  seg[e] = s;
  atomicAdd(&cnt[s], 1);
}

// ---------------- scan over NSEG counts ----------------
__global__ void k_scan1(const int* __restrict__ cnt, int* __restrict__ outIncl,
                        int* __restrict__ bsums, int n) {
  __shared__ int sd[256];
  int t = threadIdx.x;
  int base = blockIdx.x * 4096 + t * 16;
  int v[16];
  int s = 0;
#pragma unroll
  for (int j = 0; j < 16; ++j) {
    int idx = base + j;
    int x = (idx < n) ? cnt[idx] : 0;
    s += x;
    v[j] = s;
  }
  sd[t] = s;
  __syncthreads();
  for (int off = 1; off < 256; off <<= 1) {
    int add = (t >= off) ? sd[t - off] : 0;
    __syncthreads();
    sd[t] += add;
    __syncthreads();
  }
  int prev = (t > 0) ? sd[t - 1] : 0;
#pragma unroll
  for (int j = 0; j < 16; ++j) {
    int idx = base + j;
    if (idx < n) outIncl[idx] = prev + v[j];
  }
  if (t == 255) bsums[blockIdx.x] = sd[255];
}

__global__ void k_scan2(int* __restrict__ bsums, int nb) {
  __shared__ int sd[128];
  int t = threadIdx.x;
  int v = (t < nb) ? bsums[t] : 0;
  sd[t] = v;
  __syncthreads();
  for (int off = 1; off < 128; off <<= 1) {
    int add = (t >= off) ? sd[t - off] : 0;
    __syncthreads();
    sd[t] += add;
    __syncthreads();
  }
  if (t < nb) bsums[t] = sd[t] - v;  // exclusive
}

__global__ void k_scan3(int* __restrict__ offsets, const int* __restrict__ bsums, int n) {
  int i = blockIdx.x * blockDim.x + threadIdx.x;
  if (i == 0) offsets[0] = 0;
  if (i < n) offsets[i + 1] += bsums[i >> 12];
}

// ---------------- scatter into CSR ----------------
__global__ void k_scatter(const int* __restrict__ ei, const int* __restrict__ seg,
                          const int* __restrict__ offsets, int* __restrict__ cursor,
                          int* __restrict__ ssrc) {
  int e = blockIdx.x * blockDim.x + threadIdx.x;
  if (e >= N_EDGESC) return;
  int s = seg[e];
  int p = offsets[s] + atomicAdd(&cursor[s], 1);
  ssrc[p] = ei[e];
}

// ---------------- node-level mean aggregation (fp16 in/out) ----------------
// one 32-lane group per NODE; inner loop over the 8 relations; lane l = feats [4l,4l+4)
__global__ __launch_bounds__(256, 8) void k_agg(
    const __half* __restrict__ in, const int* __restrict__ offsets,
    const int* __restrict__ ssrc, __half* __restrict__ agg,
    int nodeBase, int nodeCount) {
  int t = blockIdx.x * blockDim.x + threadIdx.x;
  int un = t >> 5;
  int l = t & 31;
  if (un >= nodeCount) return;
  int node = nodeBase + un;
  for (int r = 0; r < NREL; ++r) {
    int sidx = node * NREL + r;
    int beg = offsets[sidx], end = offsets[sidx + 1];
    float4 s = make_float4(0.f, 0.f, 0.f, 0.f);
    for (int base = beg; base < end; base += 4) {
      int last = end - 1;
      int e1 = base + 1 <= last ? base + 1 : last;
      int e2 = base + 2 <= last ? base + 2 : last;
      int e3 = base + 3 <= last ? base + 3 : last;
      int i0 = ssrc[base], i1 = ssrc[e1], i2 = ssrc[e2], i3 = ssrc[e3];
      uint2 r0 = *(const uint2*)&in[(size_t)i0 * FEAT + l * 4];
      uint2 r1 = *(const uint2*)&in[(size_t)i1 * FEAT + l * 4];
      uint2 r2 = *(const uint2*)&in[(size_t)i2 * FEAT + l * 4];
      uint2 r3 = *(const uint2*)&in[(size_t)i3 * FEAT + l * 4];
      float4 v0 = h4tof4(r0), v1 = h4tof4(r1), v2 = h4tof4(r2), v3 = h4tof4(r3);
      s.x += v0.x; s.y += v0.y; s.z += v0.z; s.w += v0.w;
      if (base + 1 < end) { s.x += v1.x; s.y += v1.y; s.z += v1.z; s.w += v1.w; }
      if (base + 2 < end) { s.x += v2.x; s.y += v2.y; s.z += v2.z; s.w += v2.w; }
      if (base + 3 < end) { s.x += v3.x; s.y += v3.y; s.z += v3.z; s.w += v3.w; }
    }
    int c = end - beg;
    if (c > 1) {
      float inv = 1.0f / (float)c;
      s.x *= inv; s.y *= inv; s.z *= inv; s.w *= inv;
    }
    __half hv[4] = {__float2half(s.x), __float2half(s.y), __float2half(s.z), __float2half(s.w)};
    *(uint2*)&agg[((size_t)un * NREL + r) * FEAT + l * 4] = *(uint2*)hv;
  }
}

// ---------------- weight pack: W[8][128][128] + root[128][128] -> fp16 hi/lo ----------------
// fragment-major layout: idx = ((slot*128)+n)*8 + j, slot = kc*4+g, k = kc*32+g*8+j
__global__ void k_wpack(const float* __restrict__ W, const float* __restrict__ root,
                        __half* __restrict__ whi, __half* __restrict__ wlo) {
  int idx = blockIdx.x * 256 + threadIdx.x;
  if (idx >= WPACK_ELEMS) return;
  int j = idx & 7;
  int n = (idx >> 3) & 127;
  int slot = idx >> 10;
  int k = slot * 8 + j;
  float v = (k < 1024) ? W[(size_t)k * 128 + n] : root[(size_t)(k - 1024) * 128 + n];
  __half hi = __float2half(v);
  float lof = v - __half2float(hi);
  whi[idx] = hi;
  wlo[idx] = __float2half(lof);
}

// ---------------- LDS-free fp16 MFMA GEMM: out16 = relu(A @ (Bhi+Blo) + bias) ----------------
// 256 threads = 4 independent waves; wave owns 32 rows x 128 cols. No LDS, no barriers.
// A fragments gathered from global (64B segments, each byte read once);
// B fragments from packed Whi/Wlo (identical across blocks -> L2-resident).
__global__ __launch_bounds__(256, 3) void k_gemm_mfma(
    const __half* __restrict__ aggc,  // [rows][1024] chunk-local, fp16
    const __half* __restrict__ xin,   // [N][128] fp16 plane (layer input)
    const __half* __restrict__ Whi, const __half* __restrict__ Wlo,
    const float* __restrict__ bias, __half* __restrict__ out16,
    int n0g, int rows) {
  const int t = threadIdx.x;
  const int lane = t & 63, wave = t >> 6;
  const int l15 = lane & 15, lg = lane >> 4;
  const int wrow0 = wave * 32;
  const int m0 = blockIdx.x * 128;

  // this lane's two A rows (clamped; garbage rows masked at store)
  int r0 = m0 + wrow0 + l15;
  int r1 = r0 + 16;
  if (r0 >= rows) r0 = rows - 1;
  if (r1 >= rows) r1 = rows - 1;
  const __half* a0p = aggc + (size_t)r0 * 1024 + lg * 8;   // + kc*32
  const __half* a1p = aggc + (size_t)r1 * 1024 + lg * 8;
  const __half* x0p = xin + (size_t)(n0g + r0) * FEAT + lg * 8;  // + (kc-32)*32
  const __half* x1p = xin + (size_t)(n0g + r1) * FEAT + lg * 8;
  // B lane base: elem offset = kc*4096 + lg*1024 + (nf*16+l15)*8
  const size_t bbase = (size_t)lg * 1024 + (size_t)l15 * 8;
  const __half* bhp = Whi + bbase;
  const __half* blp = Wlo + bbase;

  f32x4 acc[2][8];
#pragma unroll
  for (int a = 0; a < 2; ++a)
#pragma unroll
    for (int b = 0; b < 8; ++b) acc[a][b] = (f32x4){0.f, 0.f, 0.f, 0.f};

  // ---- agg part: kc = 0..31 ----
  for (int kc = 0; kc < 32; ++kc) {
    f16x8 a0 = *(const f16x8*)(a0p + kc * 32);
    f16x8 a1 = *(const f16x8*)(a1p + kc * 32);
    const __half* bh = bhp + (size_t)kc * 4096;
    const __half* bl = blp + (size_t)kc * 4096;
#pragma unroll
    for (int nf = 0; nf < 8; ++nf) {
      f16x8 vh = *(const f16x8*)(bh + nf * 128);
      f16x8 vl = *(const f16x8*)(bl + nf * 128);
      acc[0][nf] = __builtin_amdgcn_mfma_f32_16x16x32_f16(a0, vh, acc[0][nf], 0, 0, 0);
      acc[0][nf] = __builtin_amdgcn_mfma_f32_16x16x32_f16(a0, vl, acc[0][nf], 0, 0, 0);
      acc[1][nf] = __builtin_amdgcn_mfma_f32_16x16x32_f16(a1, vh, acc[1][nf], 0, 0, 0);
      acc[1][nf] = __builtin_amdgcn_mfma_f32_16x16x32_f16(a1, vl, acc[1][nf], 0, 0, 0);
    }
  }
  // ---- root part: kc = 32..35 ----
  for (int kc = 0; kc < 4; ++kc) {
    f16x8 a0 = *(const f16x8*)(x0p + kc * 32);
    f16x8 a1 = *(const f16x8*)(x1p + kc * 32);
    const __half* bh = bhp + (size_t)(kc + 32) * 4096;
    const __half* bl = blp + (size_t)(kc + 32) * 4096;
#pragma unroll
    for (int nf = 0; nf < 8; ++nf) {
      f16x8 vh = *(const f16x8*)(bh + nf * 128);
      f16x8 vl = *(const f16x8*)(bl + nf * 128);
      acc[0][nf] = __builtin_amdgcn_mfma_f32_16x16x32_f16(a0, vh, acc[0][nf], 0, 0, 0);
      acc[0][nf] = __builtin_amdgcn_mfma_f32_16x16x32_f16(a0, vl, acc[0][nf], 0, 0, 0);
      acc[1][nf] = __builtin_amdgcn_mfma_f32_16x16x32_f16(a1, vh, acc[1][nf], 0, 0, 0);
      acc[1][nf] = __builtin_amdgcn_mfma_f32_16x16x32_f16(a1, vl, acc[1][nf], 0, 0, 0);
    }
  }

  // ---- epilogue: bias + relu + fp16 store ----
  float bcol[8];
#pragma unroll
  for (int nf = 0; nf < 8; ++nf) bcol[nf] = bias[nf * 16 + l15];
#pragma unroll
  for (int mf = 0; mf < 2; ++mf)
#pragma unroll
    for (int nf = 0; nf < 8; ++nf)
#pragma unroll
      for (int j = 0; j < 4; ++j) {
        int grow = m0 + wrow0 + mf * 16 + lg * 4 + j;
        if (grow < rows) {
          float v = acc[mf][nf][j] + bcol[nf];
          v = v > 0.f ? v : 0.f;
          out16[(size_t)(n0g + grow) * FEAT + nf * 16 + l15] = __float2half(v);
        }
      }
}

// ---------------- global mean pool (fp16 h) + final linear ----------------
__global__ void k_pool(const __half* __restrict__ h, const int* __restrict__ batch,
                       const float* __restrict__ lw, const float* __restrict__ lb,
                       float* __restrict__ out) {
  __shared__ float sums[8][128];
  __shared__ float prow[128];
  int gidx = blockIdx.x, t = threadIdx.x;
  int f = t & 127, grp = t >> 7;
  int lo = 0, hi = N_NODESC;
  while (lo < hi) {
    int mid = (lo + hi) >> 1;
    if (batch[mid] < gidx) lo = mid + 1; else hi = mid;
  }
  int start = lo;
  hi = N_NODESC;
  while (lo < hi) {
    int mid = (lo + hi) >> 1;
    if (batch[mid] < gidx + 1) lo = mid + 1; else hi = mid;
  }
  int end = lo;
  float s = 0.f;
  for (int n = start + grp; n < end; n += 8) s += __half2float(h[(size_t)n * FEAT + f]);
  sums[grp][f] = s;
  __syncthreads();
  if (grp == 0) {
    float tot = 0.f;
#pragma unroll
    for (int gg = 0; gg < 8; ++gg) tot += sums[gg][f];
    int c = end - start;
    prow[f] = (c > 0) ? tot / (float)c : 0.f;
  }
  __syncthreads();
  float a = 0.f;
  for (int k = grp * 16; k < grp * 16 + 16; ++k) a = fmaf(prow[k], lw[(size_t)k * FEAT + f], a);
  __syncthreads();
  sums[grp][f] = a;
  __syncthreads();
  if (grp == 0) {
    float tot = lb[f];
#pragma unroll
    for (int gg = 0; gg < 8; ++gg) tot += sums[gg][f];
    out[(size_t)gidx * FEAT + f] = tot;
  }
}

extern "C" void kernel_launch(void* const* d_in, const int* in_sizes, int n_in,
                              void* d_out, int out_size, void* d_ws, size_t ws_size,
                              hipStream_t stream) {
  const float* x = (const float*)d_in[0];
  const int* ei = (const int*)d_in[1];
  const float* eattr = (const float*)d_in[2];
  const int* batch = (const int*)d_in[3];
  const float* Wl[3] = {(const float*)d_in[4], (const float*)d_in[7], (const float*)d_in[10]};
  const float* rl[3] = {(const float*)d_in[5], (const float*)d_in[8], (const float*)d_in[11]};
  const float* bl[3] = {(const float*)d_in[6], (const float*)d_in[9], (const float*)d_in[12]};
  const float* lw = (const float*)d_in[13];
  const float* lb = (const float*)d_in[14];
  float* out = (float*)d_out;
  (void)n_in; (void)in_sizes; (void)out_size;

  // ---- workspace carve ----
  size_t pos = 0;
  char* base = (char*)d_ws;
  auto alloc = [&](size_t bytes) { char* q = base + pos; pos += align256(bytes); return q; };
  int* seg = (int*)alloc(sizeof(int) * (size_t)N_EDGESC);
  int* cntcur = (int*)alloc(sizeof(int) * (size_t)2 * NSEG);
  int* cnt = cntcur;
  int* cursor = cntcur + NSEG;
  int* offsets = (int*)alloc(sizeof(int) * (size_t)(NSEG + 1));
  int* bsums = (int*)alloc(sizeof(int) * 1024);
  int* ssrc = (int*)alloc(sizeof(int) * (size_t)N_EDGESC);
  __half* p0 = (__half*)alloc(sizeof(__half) * (size_t)NHALF);
  __half* p1 = (__half*)alloc(sizeof(__half) * (size_t)NHALF);
  __half* whi = (__half*)alloc(sizeof(__half) * (size_t)WPACK_ELEMS);
  __half* wlo = (__half*)alloc(sizeof(__half) * (size_t)WPACK_ELEMS);
  size_t remain = (ws_size > pos) ? (ws_size - pos) : 0;
  long long cn = (long long)(remain / (sizeof(__half) * NREL * FEAT));
  int chunkNodes = (cn > N_NODESC) ? N_NODESC : (int)cn;
  chunkNodes &= ~127;
  if (chunkNodes < 128) chunkNodes = 128;
  __half* aggbuf = (__half*)(base + pos);
  int nchunks = (N_NODESC + chunkNodes - 1) / chunkNodes;

  // ---- build CSR ----
  hipLaunchKernelGGL(k_zero, dim3(2048), dim3(256), 0, stream, cntcur, 2 * NSEG);
  hipLaunchKernelGGL(k_edge_hist, dim3((N_EDGESC + 255) / 256), dim3(256), 0, stream,
                     ei, eattr, seg, cnt);
  int nbScan = (NSEG + 4095) / 4096;  // 98
  hipLaunchKernelGGL(k_scan1, dim3(nbScan), dim3(256), 0, stream, cnt, offsets + 1, bsums, NSEG);
  hipLaunchKernelGGL(k_scan2, dim3(1), dim3(128), 0, stream, bsums, nbScan);
  hipLaunchKernelGGL(k_scan3, dim3((NSEG + 255) / 256), dim3(256), 0, stream, offsets, bsums, NSEG);
  hipLaunchKernelGGL(k_scatter, dim3((N_EDGESC + 255) / 256), dim3(256), 0, stream,
                     ei, seg, offsets, cursor, ssrc);

  // ---- x -> fp16 plane ----
  hipLaunchKernelGGL(k_cvt16, dim3((NHALF / 4 + 255) / 256), dim3(256), 0, stream, x, p0);

  // ---- 3 RGCN layers (fp16 activation planes) ----
  const __half* inPtr = p0;
  __half* outPtr = p1;
  for (int L = 0; L < 3; ++L) {
    hipLaunchKernelGGL(k_wpack, dim3((WPACK_ELEMS + 255) / 256), dim3(256), 0, stream,
                       Wl[L], rl[L], whi, wlo);
    for (int c = 0; c < nchunks; ++c) {
      int nodeBase = c * chunkNodes;
      int rowsC = N_NODESC - nodeBase;
      if (rowsC > chunkNodes) rowsC = chunkNodes;
      int aggBlocks = (rowsC * 32 + 255) / 256;
      hipLaunchKernelGGL(k_agg, dim3(aggBlocks), dim3(256), 0, stream,
                         inPtr, offsets, ssrc, aggbuf, nodeBase, rowsC);
      hipLaunchKernelGGL(k_gemm_mfma, dim3((rowsC + 127) / 128), dim3(256), 0, stream,
                         aggbuf, inPtr, whi, wlo, bl[L], outPtr, nodeBase, rowsC);
    }
    const __half* tmp = inPtr;
    inPtr = outPtr;
    outPtr = (__half*)tmp;
  }

  // ---- pool + final linear (last output is p1) ----
  hipLaunchKernelGGL(k_pool, dim3(NGRAPH), dim3(1024), 0, stream, p1, batch, lw, lb, out);
}

// Round 13
// 744.596 us; speedup vs baseline: 1.3549x; 1.3549x over previous
//
#include <hip/hip_runtime.h>
#include <hip/hip_fp16.h>

#define N_NODESC 50000
#define N_EDGESC 1600000
#define FEAT 128
#define NREL 8
#define NSEG (N_NODESC * NREL)
#define NGRAPH 64
#define KTOT 1152          // 8*128 agg + 128 root
#define NKC 36             // KTOT/32
#define WPACK_ELEMS (NKC * 4 * 128 * 8)  // 147456
#define NHALF (N_NODESC * FEAT)

typedef float f32x4 __attribute__((ext_vector_type(4)));
typedef _Float16 f16x8 __attribute__((ext_vector_type(8)));

static inline size_t align256(size_t x) { return (x + 255) & ~(size_t)255; }

__device__ __forceinline__ float4 h4tof4(uint2 r) {
  const __half* h = (const __half*)&r;
  return make_float4(__half2float(h[0]), __half2float(h[1]),
                     __half2float(h[2]), __half2float(h[3]));
}

// ---------------- utility: zero ints ----------------
__global__ void k_zero(int* __restrict__ p, int n) {
  int i = blockIdx.x * blockDim.x + threadIdx.x;
  int stride = gridDim.x * blockDim.x;
  for (; i < n; i += stride) p[i] = 0;
}

// ---------------- fp32 -> fp16 plane ----------------
__global__ void k_cvt16(const float* __restrict__ in, __half* __restrict__ o) {
  int i = blockIdx.x * blockDim.x + threadIdx.x;
  if (i * 4 >= NHALF) return;
  float4 v = *(const float4*)&in[i * 4];
  __half h[4] = {__float2half(v.x), __float2half(v.y), __float2half(v.z), __float2half(v.w)};
  *(uint2*)&o[(size_t)i * 4] = *(uint2*)h;
}

// ---------------- edge type + segment + histogram ----------------
__global__ void k_edge_hist(const int* __restrict__ ei, const float* __restrict__ eattr,
                            int* __restrict__ seg, int* __restrict__ cnt) {
  int e = blockIdx.x * blockDim.x + threadIdx.x;
  if (e >= N_EDGESC) return;
  int dst = ei[N_EDGESC + e];
  const float4* ap = (const float4*)(eattr + (size_t)e * 8);
  float4 a0 = ap[0], a1 = ap[1];
  int ty = 0;
  if (a0.y > 0.5f) ty = 1;
  if (a0.z > 0.5f) ty = 2;
  if (a0.w > 0.5f) ty = 3;
  if (a1.x > 0.5f) ty = 4;
  if (a1.y > 0.5f) ty = 5;
  if (a1.z > 0.5f) ty = 6;
  if (a1.w > 0.5f) ty = 7;
  int s = dst * NREL + ty;
  seg[e] = s;
  atomicAdd(&cnt[s], 1);
}

// ---------------- scan over NSEG counts ----------------
__global__ void k_scan1(const int* __restrict__ cnt, int* __restrict__ outIncl,
                        int* __restrict__ bsums, int n) {
  __shared__ int sd[256];
  int t = threadIdx.x;
  int base = blockIdx.x * 4096 + t * 16;
  int v[16];
  int s = 0;
#pragma unroll
  for (int j = 0; j < 16; ++j) {
    int idx = base + j;
    int x = (idx < n) ? cnt[idx] : 0;
    s += x;
    v[j] = s;
  }
  sd[t] = s;
  __syncthreads();
  for (int off = 1; off < 256; off <<= 1) {
    int add = (t >= off) ? sd[t - off] : 0;
    __syncthreads();
    sd[t] += add;
    __syncthreads();
  }
  int prev = (t > 0) ? sd[t - 1] : 0;
#pragma unroll
  for (int j = 0; j < 16; ++j) {
    int idx = base + j;
    if (idx < n) outIncl[idx] = prev + v[j];
  }
  if (t == 255) bsums[blockIdx.x] = sd[255];
}

__global__ void k_scan2(int* __restrict__ bsums, int nb) {
  __shared__ int sd[128];
  int t = threadIdx.x;
  int v = (t < nb) ? bsums[t] : 0;
  sd[t] = v;
  __syncthreads();
  for (int off = 1; off < 128; off <<= 1) {
    int add = (t >= off) ? sd[t - off] : 0;
    __syncthreads();
    sd[t] += add;
    __syncthreads();
  }
  if (t < nb) bsums[t] = sd[t] - v;  // exclusive
}

__global__ void k_scan3(int* __restrict__ offsets, const int* __restrict__ bsums, int n) {
  int i = blockIdx.x * blockDim.x + threadIdx.x;
  if (i == 0) offsets[0] = 0;
  if (i < n) offsets[i + 1] += bsums[i >> 12];
}

// ---------------- scatter into CSR ----------------
__global__ void k_scatter(const int* __restrict__ ei, const int* __restrict__ seg,
                          const int* __restrict__ offsets, int* __restrict__ cursor,
                          int* __restrict__ ssrc) {
  int e = blockIdx.x * blockDim.x + threadIdx.x;
  if (e >= N_EDGESC) return;
  int s = seg[e];
  int p = offsets[s] + atomicAdd(&cursor[s], 1);
  ssrc[p] = ei[e];
}

// ---------------- node-level mean aggregation (fp16 in/out) ----------------
// one 32-lane group per NODE; inner loop over the 8 relations; lane l = feats [4l,4l+4)
__global__ __launch_bounds__(256, 8) void k_agg(
    const __half* __restrict__ in, const int* __restrict__ offsets,
    const int* __restrict__ ssrc, __half* __restrict__ agg,
    int nodeBase, int nodeCount) {
  int t = blockIdx.x * blockDim.x + threadIdx.x;
  int un = t >> 5;
  int l = t & 31;
  if (un >= nodeCount) return;
  int node = nodeBase + un;
  for (int r = 0; r < NREL; ++r) {
    int sidx = node * NREL + r;
    int beg = offsets[sidx], end = offsets[sidx + 1];
    float4 s = make_float4(0.f, 0.f, 0.f, 0.f);
    for (int base = beg; base < end; base += 4) {
      int last = end - 1;
      int e1 = base + 1 <= last ? base + 1 : last;
      int e2 = base + 2 <= last ? base + 2 : last;
      int e3 = base + 3 <= last ? base + 3 : last;
      int i0 = ssrc[base], i1 = ssrc[e1], i2 = ssrc[e2], i3 = ssrc[e3];
      uint2 r0 = *(const uint2*)&in[(size_t)i0 * FEAT + l * 4];
      uint2 r1 = *(const uint2*)&in[(size_t)i1 * FEAT + l * 4];
      uint2 r2 = *(const uint2*)&in[(size_t)i2 * FEAT + l * 4];
      uint2 r3 = *(const uint2*)&in[(size_t)i3 * FEAT + l * 4];
      float4 v0 = h4tof4(r0), v1 = h4tof4(r1), v2 = h4tof4(r2), v3 = h4tof4(r3);
      s.x += v0.x; s.y += v0.y; s.z += v0.z; s.w += v0.w;
      if (base + 1 < end) { s.x += v1.x; s.y += v1.y; s.z += v1.z; s.w += v1.w; }
      if (base + 2 < end) { s.x += v2.x; s.y += v2.y; s.z += v2.z; s.w += v2.w; }
      if (base + 3 < end) { s.x += v3.x; s.y += v3.y; s.z += v3.z; s.w += v3.w; }
    }
    int c = end - beg;
    if (c > 1) {
      float inv = 1.0f / (float)c;
      s.x *= inv; s.y *= inv; s.z *= inv; s.w *= inv;
    }
    __half hv[4] = {__float2half(s.x), __float2half(s.y), __float2half(s.z), __float2half(s.w)};
    *(uint2*)&agg[((size_t)un * NREL + r) * FEAT + l * 4] = *(uint2*)hv;
  }
}

// ---------------- weight pack: W[8][128][128] + root[128][128] -> fp16 hi/lo ----------------
// fragment-major layout: idx = ((slot*128)+n)*8 + j, slot = kc*4+g, k = kc*32+g*8+j
__global__ void k_wpack(const float* __restrict__ W, const float* __restrict__ root,
                        __half* __restrict__ whi, __half* __restrict__ wlo) {
  int idx = blockIdx.x * 256 + threadIdx.x;
  if (idx >= WPACK_ELEMS) return;
  int j = idx & 7;
  int n = (idx >> 3) & 127;
  int slot = idx >> 10;
  int k = slot * 8 + j;
  float v = (k < 1024) ? W[(size_t)k * 128 + n] : root[(size_t)(k - 1024) * 128 + n];
  __half hi = __float2half(v);
  float lof = v - __half2float(hi);
  whi[idx] = hi;
  wlo[idx] = __float2half(lof);
}

// ---------------- fp16 MFMA GEMM, double-buffered LDS, 1 barrier/chunk ----------------
// block: 128 rows x 128 cols, 256 threads (4 waves), wave = 32 rows x 128 cols
__global__ __launch_bounds__(256, 3) void k_gemm_mfma(
    const __half* __restrict__ aggc,  // [rows][1024] chunk-local, fp16
    const __half* __restrict__ xin,   // [N][128] fp16 plane (layer input)
    const __half* __restrict__ Whi, const __half* __restrict__ Wlo,
    const float* __restrict__ bias, __half* __restrict__ out16,
    int n0g, int rows) {
  __shared__ __half Ah[2][4096] __attribute__((aligned(16)));   // [buf][g][row][j]
  __shared__ __half Bh[2][4096] __attribute__((aligned(16)));   // [buf][g][n][j]
  __shared__ __half Bl[2][4096] __attribute__((aligned(16)));

  const int t = threadIdx.x;
  const int lane = t & 63, wave = t >> 6;
  const int l15 = lane & 15, lg = lane >> 4;
  const int wrow0 = wave * 32;
  const int m0 = blockIdx.x * 128;
  const int srow = t >> 1, half = t & 1;

  // clamped source row for A staging (garbage rows masked at store)
  int rowc = srow;
  if (m0 + rowc >= rows) rowc = rows - 1 - m0;
  if (rowc < 0) rowc = 0;
  const __half* aggRow = aggc + (size_t)(m0 + rowc) * 1024 + half * 16;
  const __half* xRow = xin + (size_t)(n0g + m0 + rowc) * FEAT + half * 16;

  uint4 av0, av1, sbh0, sbh1, sbl0, sbl1;  // staged regs for next chunk

#define LOADC(kc)                                                         \
  {                                                                       \
    const __half* asrc = ((kc) < 32) ? (aggRow + (kc) * 32)               \
                                     : (xRow + ((kc) - 32) * 32);         \
    av0 = ((const uint4*)asrc)[0];                                        \
    av1 = ((const uint4*)asrc)[1];                                        \
    const uint4* bhs = (const uint4*)(Whi + (size_t)(kc) * 4096);         \
    const uint4* bls = (const uint4*)(Wlo + (size_t)(kc) * 4096);         \
    sbh0 = bhs[t * 2]; sbh1 = bhs[t * 2 + 1];                             \
    sbl0 = bls[t * 2]; sbl1 = bls[t * 2 + 1];                             \
  }
#define WRITEC(b)                                                         \
  {                                                                       \
    int g0 = half * 2;                                                    \
    *(uint4*)&Ah[b][(g0 * 128 + srow) * 8] = av0;                         \
    *(uint4*)&Ah[b][((g0 + 1) * 128 + srow) * 8] = av1;                   \
    ((uint4*)Bh[b])[t * 2] = sbh0; ((uint4*)Bh[b])[t * 2 + 1] = sbh1;     \
    ((uint4*)Bl[b])[t * 2] = sbl0; ((uint4*)Bl[b])[t * 2 + 1] = sbl1;     \
  }

  f32x4 acc[2][8];
#pragma unroll
  for (int a = 0; a < 2; ++a)
#pragma unroll
    for (int b = 0; b < 8; ++b) acc[a][b] = (f32x4){0.f, 0.f, 0.f, 0.f};

  LOADC(0);
  WRITEC(0);
  LOADC(1);
  __syncthreads();

  for (int kc = 0; kc < NKC; ++kc) {
    const int cur = kc & 1;
    // ---- MFMA from buf[cur] ----
    f16x8 af[2];
#pragma unroll
    for (int mf = 0; mf < 2; ++mf) {
      int ar = wrow0 + mf * 16 + l15;
      af[mf] = *(const f16x8*)&Ah[cur][(lg * 128 + ar) * 8];
    }
#pragma unroll
    for (int nf = 0; nf < 8; ++nf) {
      int bn = nf * 16 + l15;
      f16x8 vh = *(const f16x8*)&Bh[cur][(lg * 128 + bn) * 8];
      f16x8 vl = *(const f16x8*)&Bl[cur][(lg * 128 + bn) * 8];
      acc[0][nf] = __builtin_amdgcn_mfma_f32_16x16x32_f16(af[0], vh, acc[0][nf], 0, 0, 0);
      acc[0][nf] = __builtin_amdgcn_mfma_f32_16x16x32_f16(af[0], vl, acc[0][nf], 0, 0, 0);
      acc[1][nf] = __builtin_amdgcn_mfma_f32_16x16x32_f16(af[1], vh, acc[1][nf], 0, 0, 0);
      acc[1][nf] = __builtin_amdgcn_mfma_f32_16x16x32_f16(af[1], vl, acc[1][nf], 0, 0, 0);
    }
    // ---- stage next chunk: write regs(kc+1) to other buffer, issue loads(kc+2) ----
    if (kc < NKC - 1) {
      WRITEC(cur ^ 1);              // safe: buf[cur^1] last read at kc-1, barrier passed
      if (kc < NKC - 2) LOADC(kc + 2);  // in flight across next MFMA phase
      __syncthreads();              // write visible before next MFMA reads it
    }
  }
#undef LOADC
#undef WRITEC

  // ---- epilogue: bias + relu + fp16 store ----
  float bcol[8];
#pragma unroll
  for (int nf = 0; nf < 8; ++nf) bcol[nf] = bias[nf * 16 + l15];
#pragma unroll
  for (int mf = 0; mf < 2; ++mf)
#pragma unroll
    for (int nf = 0; nf < 8; ++nf)
#pragma unroll
      for (int j = 0; j < 4; ++j) {
        int grow = m0 + wrow0 + mf * 16 + lg * 4 + j;
        if (grow < rows) {
          float v = acc[mf][nf][j] + bcol[nf];
          v = v > 0.f ? v : 0.f;
          out16[(size_t)(n0g + grow) * FEAT + nf * 16 + l15] = __float2half(v);
        }
      }
}

// ---------------- global mean pool (fp16 h) + final linear ----------------
__global__ void k_pool(const __half* __restrict__ h, const int* __restrict__ batch,
                       const float* __restrict__ lw, const float* __restrict__ lb,
                       float* __restrict__ out) {
  __shared__ float sums[8][128];
  __shared__ float prow[128];
  int gidx = blockIdx.x, t = threadIdx.x;
  int f = t & 127, grp = t >> 7;
  int lo = 0, hi = N_NODESC;
  while (lo < hi) {
    int mid = (lo + hi) >> 1;
    if (batch[mid] < gidx) lo = mid + 1; else hi = mid;
  }
  int start = lo;
  hi = N_NODESC;
  while (lo < hi) {
    int mid = (lo + hi) >> 1;
    if (batch[mid] < gidx + 1) lo = mid + 1; else hi = mid;
  }
  int end = lo;
  float s = 0.f;
  for (int n = start + grp; n < end; n += 8) s += __half2float(h[(size_t)n * FEAT + f]);
  sums[grp][f] = s;
  __syncthreads();
  if (grp == 0) {
    float tot = 0.f;
#pragma unroll
    for (int gg = 0; gg < 8; ++gg) tot += sums[gg][f];
    int c = end - start;
    prow[f] = (c > 0) ? tot / (float)c : 0.f;
  }
  __syncthreads();
  float a = 0.f;
  for (int k = grp * 16; k < grp * 16 + 16; ++k) a = fmaf(prow[k], lw[(size_t)k * FEAT + f], a);
  __syncthreads();
  sums[grp][f] = a;
  __syncthreads();
  if (grp == 0) {
    float tot = lb[f];
#pragma unroll
    for (int gg = 0; gg < 8; ++gg) tot += sums[gg][f];
    out[(size_t)gidx * FEAT + f] = tot;
  }
}

extern "C" void kernel_launch(void* const* d_in, const int* in_sizes, int n_in,
                              void* d_out, int out_size, void* d_ws, size_t ws_size,
                              hipStream_t stream) {
  const float* x = (const float*)d_in[0];
  const int* ei = (const int*)d_in[1];
  const float* eattr = (const float*)d_in[2];
  const int* batch = (const int*)d_in[3];
  const float* Wl[3] = {(const float*)d_in[4], (const float*)d_in[7], (const float*)d_in[10]};
  const float* rl[3] = {(const float*)d_in[5], (const float*)d_in[8], (const float*)d_in[11]};
  const float* bl[3] = {(const float*)d_in[6], (const float*)d_in[9], (const float*)d_in[12]};
  const float* lw = (const float*)d_in[13];
  const float* lb = (const float*)d_in[14];
  float* out = (float*)d_out;
  (void)n_in; (void)in_sizes; (void)out_size;

  // ---- workspace carve ----
  size_t pos = 0;
  char* base = (char*)d_ws;
  auto alloc = [&](size_t bytes) { char* q = base + pos; pos += align256(bytes); return q; };
  int* seg = (int*)alloc(sizeof(int) * (size_t)N_EDGESC);
  int* cntcur = (int*)alloc(sizeof(int) * (size_t)2 * NSEG);
  int* cnt = cntcur;
  int* cursor = cntcur + NSEG;
  int* offsets = (int*)alloc(sizeof(int) * (size_t)(NSEG + 1));
  int* bsums = (int*)alloc(sizeof(int) * 1024);
  int* ssrc = (int*)alloc(sizeof(int) * (size_t)N_EDGESC);
  __half* p0 = (__half*)alloc(sizeof(__half) * (size_t)NHALF);
  __half* p1 = (__half*)alloc(sizeof(__half) * (size_t)NHALF);
  __half* whi = (__half*)alloc(sizeof(__half) * (size_t)WPACK_ELEMS);
  __half* wlo = (__half*)alloc(sizeof(__half) * (size_t)WPACK_ELEMS);
  size_t remain = (ws_size > pos) ? (ws_size - pos) : 0;
  long long cn = (long long)(remain / (sizeof(__half) * NREL * FEAT));
  int chunkNodes = (cn > N_NODESC) ? N_NODESC : (int)cn;
  chunkNodes &= ~127;
  if (chunkNodes < 128) chunkNodes = 128;
  __half* aggbuf = (__half*)(base + pos);
  int nchunks = (N_NODESC + chunkNodes - 1) / chunkNodes;

  // ---- build CSR ----
  hipLaunchKernelGGL(k_zero, dim3(2048), dim3(256), 0, stream, cntcur, 2 * NSEG);
  hipLaunchKernelGGL(k_edge_hist, dim3((N_EDGESC + 255) / 256), dim3(256), 0, stream,
                     ei, eattr, seg, cnt);
  int nbScan = (NSEG + 4095) / 4096;  // 98
  hipLaunchKernelGGL(k_scan1, dim3(nbScan), dim3(256), 0, stream, cnt, offsets + 1, bsums, NSEG);
  hipLaunchKernelGGL(k_scan2, dim3(1), dim3(128), 0, stream, bsums, nbScan);
  hipLaunchKernelGGL(k_scan3, dim3((NSEG + 255) / 256), dim3(256), 0, stream, offsets, bsums, NSEG);
  hipLaunchKernelGGL(k_scatter, dim3((N_EDGESC + 255) / 256), dim3(256), 0, stream,
                     ei, seg, offsets, cursor, ssrc);

  // ---- x -> fp16 plane ----
  hipLaunchKernelGGL(k_cvt16, dim3((NHALF / 4 + 255) / 256), dim3(256), 0, stream, x, p0);

  // ---- 3 RGCN layers (fp16 activation planes) ----
  const __half* inPtr = p0;
  __half* outPtr = p1;
  for (int L = 0; L < 3; ++L) {
    hipLaunchKernelGGL(k_wpack, dim3((WPACK_ELEMS + 255) / 256), dim3(256), 0, stream,
                       Wl[L], rl[L], whi, wlo);
    for (int c = 0; c < nchunks; ++c) {
      int nodeBase = c * chunkNodes;
      int rowsC = N_NODESC - nodeBase;
      if (rowsC > chunkNodes) rowsC = chunkNodes;
      int aggBlocks = (rowsC * 32 + 255) / 256;
      hipLaunchKernelGGL(k_agg, dim3(aggBlocks), dim3(256), 0, stream,
                         inPtr, offsets, ssrc, aggbuf, nodeBase, rowsC);
      hipLaunchKernelGGL(k_gemm_mfma, dim3((rowsC + 127) / 128), dim3(256), 0, stream,
                         aggbuf, inPtr, whi, wlo, bl[L], outPtr, nodeBase, rowsC);
    }
    const __half* tmp = inPtr;
    inPtr = outPtr;
    outPtr = (__half*)tmp;
  }

  // ---- pool + final linear (last output is p1) ----
  hipLaunchKernelGGL(k_pool, dim3(NGRAPH), dim3(1024), 0, stream, p1, batch, lw, lb, out);
}